// Round 7
// baseline (211.304 us; speedup 1.0000x reference)
//
#include <hip/hip_runtime.h>

// GroupGSDConv round 11: register-rich pipelining + conflict-floor LDS.
// Round-10 post-mortem: launch_bounds(1024,4) squeezed VGPR_Count to 64;
// after 32 acc regs only ~2 loads in flight -> every latency exposed ->
// phases serial (45us LDS + 23us L1 + 23us MFMA ~= 88us measured).
// Fixes:
//  (1) 512-thr blocks, launch_bounds(512,2): 256-VGPR budget. Per item,
//      batch-load all 36 A-frags into uint4 af[36] (144 VGPR, static
//      indices) -> 36 VMEM in flight; compiler pipelines ds_reads deeply.
//  (2) h-plane LDS layout (NO xor swizzle): plane = [h][pix] half-planes
//      of 16B/pixel. A b128 read walks pix at 16B stride -> 8 consecutive
//      pixels span all 32 banks -> hardware floor (8cyc/KB), 0 conflicts.
//      Staging stays global_load_lds-linear: chunk q = p*1232 + pix,
//      source address picks ic-half p directly. Plane stride padded to
//      39936B so set-38 tail writes land in per-plane pad (never read).
//  Waves = 8 y-pairs, each runs ALL items (item-outer, one acc pair live).
//  1 block/CU (159744B LDS), 2 serial blocks/CU. XCD swizzle kept.
// Prep kernel unchanged from round 10 (xb16 ks-plane bf16 + desc/wpack).

#define HW_ 128
#define C_ 64
#define B_ 16
#define EX 44
#define EY 28
#define NPIX (EY * EX)              // 1232 staged pixels
#define NSETS 39                    // ceil(2464/64) wave-chunk sets
#define HALFDW (NPIX * 4)           // 4928 dwords per half-plane
#define PLANEDW (NSETS * 64 * 4)    // 9984 dwords (39936 B) per plane
#define PADW 140
#define PLANE_STRIDE (PADW * PADW * 16)  // shorts per ks-plane (313600)
#define MAX_ITEMS 12
#define WS_WPACK_OFF 1024
#define WS_XB16_OFF (1 << 20)
#define XB16_BYTES ((size_t)B_ * 4 * PLANE_STRIDE * 2)  // 40,140,800

// desc layout (ints):
//  [0..63]   perm (sorted-by-dilation channel ids)
//  [64]      cnt (number of items)
//  [66+i]    dilation of item i      (i < 12)
//  [78+i]    start of item i in perm
//  [90+i]    g (row count) of item i

typedef __attribute__((ext_vector_type(8))) short short8;
typedef __attribute__((ext_vector_type(16))) float floatx16;

__device__ __forceinline__ unsigned bf16rne(float f) {
  unsigned u = __float_as_uint(f);
  return (u + 0x7FFFu + ((u >> 16) & 1u)) >> 16;  // round-nearest-even
}

#define GLOAD_LDS16(g, l)                                   \
  __builtin_amdgcn_global_load_lds(                         \
      (const __attribute__((address_space(1))) void*)(g),   \
      (__attribute__((address_space(3))) void*)(l), 16, 0, 0)

__global__ __launch_bounds__(256) void gsd_prep(
    const float* __restrict__ x, const int* __restrict__ offsets,
    const float* __restrict__ w, int* __restrict__ desc,
    uint4* __restrict__ wpack, unsigned short* __restrict__ xb16,
    const int nrow) {
  const int bid = blockIdx.x;
  const int tid = threadIdx.x;

  if (bid < nrow) {
    // ---- transpose+convert one padded row into 4 ks-planes ----
    // per plane-row: 140 px * 16 ch * 2B = 4480 B = 280 uint4 (2/px)
    const int b = bid / PADW, py = bid - b * PADW;
    uint4* o4 = (uint4*)xb16;
    const size_t pb0 = ((size_t)b * 4) * 39200 + (size_t)py * 280;
    const uint4 z = make_uint4(0, 0, 0, 0);
    if (py < 6 || py >= PADW - 6) {
      for (int i = tid; i < 1120; i += 256) {
        const int ks = i / 280, r = i - ks * 280;
        o4[pb0 + (size_t)ks * 39200 + r] = z;
      }
      return;
    }
    // x-pads: per plane-row, uint4 0..11 and 268..279
    if (tid < 96) {
      const int ks = tid / 24, rr = tid - ks * 24;
      const int idx = rr < 12 ? rr : 256 + rr;
      o4[pb0 + (size_t)ks * 39200 + idx] = z;
    }
    const int y = py - 6;
    __shared__ unsigned l32[128 * 33];  // [x][c-pair], +1 pad
    const int xx = tid & 127, ph = tid >> 7;
    const float* xp = x + (size_t)b * (C_ * HW_ * HW_) + y * HW_ + xx;
#pragma unroll 4
    for (int p = ph; p < 32; p += 2) {
      const float v0 = xp[(2 * p) * (HW_ * HW_)];
      const float v1 = xp[(2 * p + 1) * (HW_ * HW_)];
      l32[xx * 33 + p] = bf16rne(v0) | (bf16rne(v1) << 16);
    }
    __syncthreads();
#pragma unroll 4
    for (int ch = tid; ch < 1024; ch += 256) {  // 4 planes * 128 px * 2
      const int ks = ch >> 8, r = ch & 255;
      const unsigned* s = &l32[(r >> 1) * 33 + ks * 8 + (r & 1) * 4];
      o4[pb0 + (size_t)ks * 39200 + 12 + r] = make_uint4(s[0], s[1], s[2], s[3]);
    }
    return;
  }

  // ---- setup role (tail blocks; every block recomputes sd) ----
  __shared__ int sd[128];
  __shared__ int soffs[C_];
  if (tid < C_) soffs[tid] = offsets[tid];
  __syncthreads();
  if (tid < C_) {  // parallel stable rank sort by (dilation, channel)
    const int key = soffs[tid];
    int rank = 0;
    for (int c = 0; c < C_; ++c) {
      const int kc = soffs[c];
      rank += (int)((kc < key) | ((kc == key) & (c < tid)));
    }
    sd[rank] = tid;
  }
  __syncthreads();
  if (tid == 0) {
    // dilation-pure items: one per contiguous run (split at 32 rows)
    int ni = 0, c = 0;
    while (c < C_ && ni < MAX_ITEMS) {
      const int d = soffs[sd[c]];
      int e = c;
      while (e < C_ && soffs[sd[e]] == d) ++e;  // run [c, e)
      for (int st = c; st < e && ni < MAX_ITEMS; st += 32) {
        sd[66 + ni] = d;
        sd[78 + ni] = st;
        sd[90 + ni] = (e - st) < 32 ? (e - st) : 32;
        ++ni;
      }
      c = e;
    }
    sd[64] = ni;
  }
  __syncthreads();

  const int sbid = bid - nrow;
  if (sbid == 0) {
    if (tid < 102) desc[tid] = sd[tid];
    return;
  }
  const int wix = sbid - 1;
  if (wix >= sd[64]) return;
  const int start = sd[78 + wix];
  const int g = sd[90 + wix];

  // Pack A-frags: wpack[wix*2304 + ((ks*9+tap)*64+lane)], element layout
  // m = lane&31 (compressed row), k = (lane>>5)*8 + j, ic = ks*16 + k.
  for (int i = tid; i < 4 * 9 * 64; i += 256) {
    const int ks = i / 576;
    const int r = i % 576;
    const int tap = r >> 6;
    const int lane = r & 63;
    const int m = lane & 31, hh = lane >> 5;
    const bool act = m < g;
    const int oc = act ? sd[start + m] : 0;
    unsigned ww[4];
    for (int jj = 0; jj < 4; ++jj) {
      float v0 = 0.f, v1 = 0.f;
      if (act) {
        const int ic0 = ks * 16 + hh * 8 + jj * 2;
        v0 = w[(oc * C_ + ic0) * 9 + tap];
        v1 = w[(oc * C_ + ic0 + 1) * 9 + tap];
      }
      ww[jj] = bf16rne(v0) | (bf16rne(v1) << 16);
    }
    wpack[(size_t)wix * 2304 + i] = make_uint4(ww[0], ww[1], ww[2], ww[3]);
  }
}

template <bool PRE>
__global__ __launch_bounds__(512, 2) void gsd_conv(
    const float* __restrict__ x, const unsigned short* __restrict__ xb16,
    const int* __restrict__ desc, const uint4* __restrict__ wpack,
    float* __restrict__ out) {
  const int tid = threadIdx.x;
  const int bid0 = blockIdx.x;
  const int gxid = (bid0 & 7) * 64 + (bid0 >> 3);  // XCD swizzle (512%8==0)
  const int b = gxid >> 5;
  const int yt = (gxid >> 2) & 7;
  const int xt = gxid & 3;
  const int y0 = yt * 16, x0 = xt * 32;

  const int lane = tid & 63;
  const int n = lane & 31;    // MFMA B col -> output x
  const int h = lane >> 5;    // k-half
  const int wv = tid >> 6;    // 8 waves = 8 y-pairs
  const int yb = wv * 2;      // this wave's rows: yb, yb+1

  // 4 planes, each [h][pix] half-planes of 16B/px: 159744 B -> 1 blk/CU
  __shared__ __align__(16) unsigned ldsbuf[4 * PLANEDW];

  if constexpr (PRE) {
    // ---- stage all 4 planes: 20 async 16B chunks/wave, zero VALU ----
    // Chunk q -> LDS dst byte = q*16 (linear); content: half-plane
    // p = q>=NPIX, pixel pix = q - p*NPIX  (NO swizzle; h-plane layout
    // is conflict-free by construction). Tail (q>=2464) -> plane pad.
    const unsigned short* xbase = xb16 + (size_t)b * 4 * PLANE_STRIDE;
    int srcoff[5];
#pragma unroll
    for (int j = 0; j < 5; ++j) {
      int q = (wv + j * 8) * 64 + lane;
      if (q > 2 * NPIX - 1) q = 2 * NPIX - 1;  // src clamp for tail
      const int p = q >= NPIX ? 1 : 0;
      const int pix = q - p * NPIX;
      const int yy = pix / EX, xx = pix - yy * EX;
      srcoff[j] = ((y0 + yy) * PADW + (x0 + xx)) * 16 + p * 8;
    }
#pragma unroll
    for (int ks = 0; ks < 4; ++ks) {
      const unsigned short* xp = xbase + (size_t)ks * PLANE_STRIDE;
#pragma unroll
      for (int j = 0; j < 5; ++j) {
        if (j < 4 || wv < 7) {  // sets 0..38 only
          GLOAD_LDS16(xp + srcoff[j],
                      &ldsbuf[ks * PLANEDW + (wv + j * 8) * 256]);
        }
      }
    }
  } else {
    // ---- fallback: stage 4 planes via fp32 loads + VALU convert ----
    const int slx = tid & 63;
    const int sq = (tid >> 6) & 3;  // ic-quad: p = sq>>1
    const int sy2 = tid >> 8;       // 0..1
    const float* xb = x + (size_t)b * (C_ * HW_ * HW_);
    const int gx = x0 - 6 + slx;
    const int gxc = gx < 0 ? 0 : (gx > 127 ? 127 : gx);
    const bool xin = ((unsigned)gx < 128u) & (slx < EX);
    for (int ks = 0; ks < 4; ++ks) {
      const float* xp = xb + (size_t)(ks * 16 + sq * 4) * (HW_ * HW_);
#pragma unroll 2
      for (int yy = sy2; yy < EY; yy += 2) {
        const int gy = y0 - 6 + yy;
        const int gyc = gy < 0 ? 0 : (gy > 127 ? 127 : gy);
        const bool ok = xin & ((unsigned)gy < 128u);
        const float* p = xp + gyc * HW_ + gxc;
        float v0 = p[0];
        float v1 = p[HW_ * HW_];
        float v2 = p[2 * HW_ * HW_];
        float v3 = p[3 * HW_ * HW_];
        if (!ok) { v0 = v1 = v2 = v3 = 0.f; }
        const unsigned lo = bf16rne(v0) | (bf16rne(v1) << 16);
        const unsigned hi = bf16rne(v2) | (bf16rne(v3) << 16);
        if (slx < EX) {
          const int pix = yy * EX + slx;
          const int dws = ks * PLANEDW + (sq >> 1) * HALFDW + pix * 4 +
                          ((sq & 1) << 1);
          *reinterpret_cast<uint2*>(&ldsbuf[dws]) = make_uint2(lo, hi);
        }
      }
    }
  }
  __syncthreads();  // single barrier; compute is barrier-free

  const int cnt = __builtin_amdgcn_readfirstlane(desc[64]);
  const int hbase = h * HALFDW;

  // ---- item-outer compute: batch af[36] per item, one acc pair live ----
  for (int s = 0; s < cnt; ++s) {
    const int d = __builtin_amdgcn_readfirstlane(desc[66 + s]);
    const int start = __builtin_amdgcn_readfirstlane(desc[78 + s]);
    const int g = __builtin_amdgcn_readfirstlane(desc[90 + s]);

    // batch-issue all 36 A-frag loads (static indices -> registers)
    const uint4* wp = wpack + (size_t)s * 2304 + lane;
    uint4 af[36];
#pragma unroll
    for (int i = 0; i < 36; ++i) af[i] = wp[i * 64];

    floatx16 acc0, acc1;
#pragma unroll
    for (int e = 0; e < 16; ++e) { acc0[e] = 0.f; acc1[e] = 0.f; }

#pragma unroll
    for (int i = 0; i < 36; ++i) {
      const int ks = i / 9, tap = i % 9;
      const int ky = tap / 3 - 1, kx = tap % 3 - 1;
      const int prow = yb + ky * d + 6;
      const int pxb = n + kx * d + 6;
      const int pix0 = prow * EX + pxb;
      const int pix1 = pix0 + EX;
      const unsigned* cb = &ldsbuf[ks * PLANEDW + hbase];
      const short8 bf0 = *reinterpret_cast<const short8*>(&cb[pix0 * 4]);
      const short8 bf1 = *reinterpret_cast<const short8*>(&cb[pix1 * 4]);
      const short8 a8 = __builtin_bit_cast(short8, af[i]);
      acc0 = __builtin_amdgcn_mfma_f32_32x32x16_bf16(a8, bf0, acc0, 0, 0, 0);
      acc1 = __builtin_amdgcn_mfma_f32_32x32x16_bf16(a8, bf1, acc1, 0, 0, 0);
    }

    // ---- store item s: D col=lane&31 -> x, row=(reg&3)+8*(reg>>2)+4*h ----
    // row is the compressed item row; mask row<g, oc = perm[start+row].
#pragma unroll
    for (int reg = 0; reg < 16; ++reg) {
      const int row = (reg & 3) + 8 * (reg >> 2) + 4 * h;
      if (row < g) {
        const int oc = desc[start + row];
        float* op =
            &out[((size_t)(b * C_ + oc) * HW_ + (y0 + yb)) * HW_ + x0 + n];
        op[0] = acc0[reg];
        op[HW_] = acc1[reg];
      }
    }
  }
}

extern "C" void kernel_launch(void* const* d_in, const int* in_sizes, int n_in,
                              void* d_out, int out_size, void* d_ws,
                              size_t ws_size, hipStream_t stream) {
  const float* x = (const float*)d_in[0];    // [16,64,128,128] fp32
  const float* w = (const float*)d_in[1];    // [64,64,3,3] fp32
  const int* offsets = (const int*)d_in[2];  // [64] int32 in [1,6]
  float* out = (float*)d_out;                // [16,64,128,128] fp32

  int* desc = (int*)d_ws;
  uint4* wpack = (uint4*)((char*)d_ws + WS_WPACK_OFF);  // 442368 B
  unsigned short* xb16 = (unsigned short*)((char*)d_ws + WS_XB16_OFF);

  // Fast path needs 1 MB (desc+wpack) + 40.1 MB (xb16) of workspace.
  const bool pre = ws_size >= (size_t)WS_XB16_OFF + XB16_BYTES;
  const int nrow = pre ? B_ * PADW : 0;

  gsd_prep<<<dim3(nrow + 1 + MAX_ITEMS), 256, 0, stream>>>(
      x, offsets, w, desc, wpack, xb16, nrow);
  if (pre) {
    gsd_conv<true><<<dim3(B_ * 8 * 4), 512, 0, stream>>>(
        x, xb16, desc, wpack, out);
  } else {
    gsd_conv<false><<<dim3(B_ * 8 * 4), 512, 0, stream>>>(
        x, xb16, desc, wpack, out);
  }
}

// Round 8
// 200.421 us; speedup vs baseline: 1.0543x; 1.0543x over previous
//
#include <hip/hip_runtime.h>

// GroupGSDConv round 12: 12-wave slot-parallel item-outer (3 waves/SIMD,
// 170-VGPR cap). Round-11 post-mortem: conflict-free LDS worked (0
// conflicts) but 2 waves/SIMD + VGPR 88 left pipes idle 55% (100us).
// Occupancy-register tradeoff: 4/SIMD caps VGPR at 128 (R10: starved),
// 2/SIMD allows 256 but can't hide latency (R9/R11). This round: 3/SIMD
// (768 thr, launch_bounds(768,3) -> 170 VGPR cap).
// Structure: all 4 ks-planes resident in LDS ([ks][h][pix] h-plane
// layout, 39936 dwords = 159744B, conflict-free b128 reads), ONE barrier.
// Work = slots (item, y-quad): slot s -> item s%cnt, rows 4*(s/cnt);
// wave w runs slots {w, w+12} (cnt=6: same item both slots). Per slot
// only acc[4] (64 VGPR) live; per ks af[9] batch (36 VGPR) + bf[4] read
// batches -> ~150 VGPR, deep pipelining headroom.
// Staging: 13 rounds x 768 chunks of global_load_lds(16B), linear dst,
// source picks (plane, half, pixel) directly. Tail clamped into the
// 2048B LDS pad. XCD swizzle kept (512%8==0). Prep unchanged.

#define HW_ 128
#define C_ 64
#define B_ 16
#define EX 44
#define EY 28
#define NPIX (EY * EX)              // 1232 staged pixels
#define CHPP (NPIX * 2)             // 2464 16B chunks per plane
#define NCHTOT (CHPP * 4)           // 9856 chunks total
#define NROUND 13                   // ceil(9856/768)
#define LDSDW (NROUND * 768 * 4)    // 39936 dwords = 159744 B
#define PLDW (CHPP * 4)             // 9856 dwords per plane
#define HDW (NPIX * 4)              // 4928 dwords per half-plane
#define PADW 140
#define PLANE_STRIDE (PADW * PADW * 16)  // shorts per ks-plane (313600)
#define MAX_ITEMS 12
#define WS_WPACK_OFF 1024
#define WS_XB16_OFF (1 << 20)
#define XB16_BYTES ((size_t)B_ * 4 * PLANE_STRIDE * 2)  // 40,140,800

// desc layout (ints):
//  [0..63]   perm (sorted-by-dilation channel ids)
//  [64]      cnt (number of items)
//  [66+i]    dilation of item i      (i < 12)
//  [78+i]    start of item i in perm
//  [90+i]    g (row count) of item i

typedef __attribute__((ext_vector_type(8))) short short8;
typedef __attribute__((ext_vector_type(16))) float floatx16;

__device__ __forceinline__ unsigned bf16rne(float f) {
  unsigned u = __float_as_uint(f);
  return (u + 0x7FFFu + ((u >> 16) & 1u)) >> 16;  // round-nearest-even
}

#define GLOAD_LDS16(g, l)                                   \
  __builtin_amdgcn_global_load_lds(                         \
      (const __attribute__((address_space(1))) void*)(g),   \
      (__attribute__((address_space(3))) void*)(l), 16, 0, 0)

__global__ __launch_bounds__(256) void gsd_prep(
    const float* __restrict__ x, const int* __restrict__ offsets,
    const float* __restrict__ w, int* __restrict__ desc,
    uint4* __restrict__ wpack, unsigned short* __restrict__ xb16,
    const int nrow) {
  const int bid = blockIdx.x;
  const int tid = threadIdx.x;

  if (bid < nrow) {
    // ---- transpose+convert one padded row into 4 ks-planes ----
    // per plane-row: 140 px * 16 ch * 2B = 4480 B = 280 uint4 (2/px)
    const int b = bid / PADW, py = bid - b * PADW;
    uint4* o4 = (uint4*)xb16;
    const size_t pb0 = ((size_t)b * 4) * 39200 + (size_t)py * 280;
    const uint4 z = make_uint4(0, 0, 0, 0);
    if (py < 6 || py >= PADW - 6) {
      for (int i = tid; i < 1120; i += 256) {
        const int ks = i / 280, r = i - ks * 280;
        o4[pb0 + (size_t)ks * 39200 + r] = z;
      }
      return;
    }
    // x-pads: per plane-row, uint4 0..11 and 268..279
    if (tid < 96) {
      const int ks = tid / 24, rr = tid - ks * 24;
      const int idx = rr < 12 ? rr : 256 + rr;
      o4[pb0 + (size_t)ks * 39200 + idx] = z;
    }
    const int y = py - 6;
    __shared__ unsigned l32[128 * 33];  // [x][c-pair], +1 pad
    const int xx = tid & 127, ph = tid >> 7;
    const float* xp = x + (size_t)b * (C_ * HW_ * HW_) + y * HW_ + xx;
#pragma unroll 4
    for (int p = ph; p < 32; p += 2) {
      const float v0 = xp[(2 * p) * (HW_ * HW_)];
      const float v1 = xp[(2 * p + 1) * (HW_ * HW_)];
      l32[xx * 33 + p] = bf16rne(v0) | (bf16rne(v1) << 16);
    }
    __syncthreads();
#pragma unroll 4
    for (int ch = tid; ch < 1024; ch += 256) {  // 4 planes * 128 px * 2
      const int ks = ch >> 8, r = ch & 255;
      const unsigned* s = &l32[(r >> 1) * 33 + ks * 8 + (r & 1) * 4];
      o4[pb0 + (size_t)ks * 39200 + 12 + r] = make_uint4(s[0], s[1], s[2], s[3]);
    }
    return;
  }

  // ---- setup role (tail blocks; every block recomputes sd) ----
  __shared__ int sd[128];
  __shared__ int soffs[C_];
  if (tid < C_) soffs[tid] = offsets[tid];
  __syncthreads();
  if (tid < C_) {  // parallel stable rank sort by (dilation, channel)
    const int key = soffs[tid];
    int rank = 0;
    for (int c = 0; c < C_; ++c) {
      const int kc = soffs[c];
      rank += (int)((kc < key) | ((kc == key) & (c < tid)));
    }
    sd[rank] = tid;
  }
  __syncthreads();
  if (tid == 0) {
    // dilation-pure items: one per contiguous run (split at 32 rows)
    int ni = 0, c = 0;
    while (c < C_ && ni < MAX_ITEMS) {
      const int d = soffs[sd[c]];
      int e = c;
      while (e < C_ && soffs[sd[e]] == d) ++e;  // run [c, e)
      for (int st = c; st < e && ni < MAX_ITEMS; st += 32) {
        sd[66 + ni] = d;
        sd[78 + ni] = st;
        sd[90 + ni] = (e - st) < 32 ? (e - st) : 32;
        ++ni;
      }
      c = e;
    }
    sd[64] = ni;
  }
  __syncthreads();

  const int sbid = bid - nrow;
  if (sbid == 0) {
    if (tid < 102) desc[tid] = sd[tid];
    return;
  }
  const int wix = sbid - 1;
  if (wix >= sd[64]) return;
  const int start = sd[78 + wix];
  const int g = sd[90 + wix];

  // Pack A-frags: wpack[wix*2304 + ((ks*9+tap)*64+lane)], element layout
  // m = lane&31 (compressed row), k = (lane>>5)*8 + j, ic = ks*16 + k.
  for (int i = tid; i < 4 * 9 * 64; i += 256) {
    const int ks = i / 576;
    const int r = i % 576;
    const int tap = r >> 6;
    const int lane = r & 63;
    const int m = lane & 31, hh = lane >> 5;
    const bool act = m < g;
    const int oc = act ? sd[start + m] : 0;
    unsigned ww[4];
    for (int jj = 0; jj < 4; ++jj) {
      float v0 = 0.f, v1 = 0.f;
      if (act) {
        const int ic0 = ks * 16 + hh * 8 + jj * 2;
        v0 = w[(oc * C_ + ic0) * 9 + tap];
        v1 = w[(oc * C_ + ic0 + 1) * 9 + tap];
      }
      ww[jj] = bf16rne(v0) | (bf16rne(v1) << 16);
    }
    wpack[(size_t)wix * 2304 + i] = make_uint4(ww[0], ww[1], ww[2], ww[3]);
  }
}

template <bool PRE>
__global__ __launch_bounds__(768, 3) void gsd_conv(
    const float* __restrict__ x, const unsigned short* __restrict__ xb16,
    const int* __restrict__ desc, const uint4* __restrict__ wpack,
    float* __restrict__ out) {
  const int tid = threadIdx.x;
  const int bid0 = blockIdx.x;
  const int gxid = (bid0 & 7) * 64 + (bid0 >> 3);  // XCD swizzle (512%8==0)
  const int b = gxid >> 5;
  const int yt = (gxid >> 2) & 7;
  const int xt = gxid & 3;
  const int y0 = yt * 16, x0 = xt * 32;

  const int lane = tid & 63;
  const int n = lane & 31;    // MFMA B col -> output x
  const int h = lane >> 5;    // k-half
  const int wv = tid >> 6;    // 12 waves

  // 4 ks-planes, [ks][h][pix] h-plane layout: 159744 B -> 1 block/CU
  __shared__ __align__(16) unsigned ldsbuf[LDSDW];

  if constexpr (PRE) {
    // ---- stage: 13 rounds x 768 async 16B chunks, zero VALU ----
    // Chunk q: plane = q/2464, c = q%2464, half p = c>=1232,
    // pix = c - p*1232. LDS dst = q*16 (linear). Tail (q>=9856) clamps
    // source and lands in dwords 39424..39935 (pad, never read).
    const unsigned short* xbase = xb16 + (size_t)b * 4 * PLANE_STRIDE;
    int srcoff[NROUND];
#pragma unroll
    for (int r = 0; r < NROUND; ++r) {
      int q = r * 768 + tid;
      if (q > NCHTOT - 1) q = NCHTOT - 1;
      const int plane = q / CHPP;
      const int c = q - plane * CHPP;
      const int p = c >= NPIX ? 1 : 0;
      const int pix = c - p * NPIX;
      const int yy = pix / EX, xx = pix - yy * EX;
      srcoff[r] = plane * PLANE_STRIDE +
                  ((y0 + yy) * PADW + (x0 + xx)) * 16 + p * 8;
    }
#pragma unroll
    for (int r = 0; r < NROUND; ++r) {
      GLOAD_LDS16(xbase + srcoff[r], &ldsbuf[(r * 768 + wv * 64) * 4]);
    }
  } else {
    // ---- fallback: stage 4 planes via fp32 loads + VALU convert ----
    const int slx = tid & 63;
    const int grp = tid >> 6;       // 0..11
    const int sq = grp & 3;         // ic-quad (4 ch); half p = sq>>1
    const int sy3 = grp >> 2;       // 0..2, y stride 3
    const float* xb = x + (size_t)b * (C_ * HW_ * HW_);
    const int gx = x0 - 6 + slx;
    const int gxc = gx < 0 ? 0 : (gx > 127 ? 127 : gx);
    const bool xin = ((unsigned)gx < 128u) & (slx < EX);
    for (int ks = 0; ks < 4; ++ks) {
      const float* xp = xb + (size_t)(ks * 16 + sq * 4) * (HW_ * HW_);
      for (int yy = sy3; yy < EY; yy += 3) {
        const int gy = y0 - 6 + yy;
        const int gyc = gy < 0 ? 0 : (gy > 127 ? 127 : gy);
        const bool ok = xin & ((unsigned)gy < 128u);
        const float* p = xp + gyc * HW_ + gxc;
        float v0 = p[0];
        float v1 = p[HW_ * HW_];
        float v2 = p[2 * HW_ * HW_];
        float v3 = p[3 * HW_ * HW_];
        if (!ok) { v0 = v1 = v2 = v3 = 0.f; }
        const unsigned lo = bf16rne(v0) | (bf16rne(v1) << 16);
        const unsigned hi = bf16rne(v2) | (bf16rne(v3) << 16);
        if (slx < EX) {
          const int pix = yy * EX + slx;
          const int dws =
              ks * PLDW + (sq >> 1) * HDW + pix * 4 + ((sq & 1) << 1);
          *reinterpret_cast<uint2*>(&ldsbuf[dws]) = make_uint2(lo, hi);
        }
      }
    }
  }
  __syncthreads();  // single barrier; compute is barrier-free

  const int cnt = __builtin_amdgcn_readfirstlane(desc[64]);

  // ---- slot-parallel item-outer compute ----
  // slot s -> item s%cnt, y-quad s/cnt (rows 4*quad .. +3).
  for (int s = wv; s < 4 * cnt; s += 12) {
    const int quad = s / cnt;
    const int item = s - quad * cnt;
    const int d = __builtin_amdgcn_readfirstlane(desc[66 + item]);
    const int start = __builtin_amdgcn_readfirstlane(desc[78 + item]);
    const int g = __builtin_amdgcn_readfirstlane(desc[90 + item]);
    const int yq = quad * 4;

    floatx16 acc[4];
#pragma unroll
    for (int r = 0; r < 4; ++r)
#pragma unroll
      for (int e = 0; e < 16; ++e) acc[r][e] = 0.f;

#pragma unroll
    for (int ks = 0; ks < 4; ++ks) {
      // batch the 9 A-frag loads for this ks (static indices)
      const uint4* wp = wpack + ((size_t)item * 4 + ks) * 576 + lane;
      uint4 af[9];
#pragma unroll
      for (int t = 0; t < 9; ++t) af[t] = wp[t * 64];
      const unsigned* cb = &ldsbuf[ks * PLDW + h * HDW];
#pragma unroll
      for (int tap = 0; tap < 9; ++tap) {
        const int ky = tap / 3 - 1, kx = tap % 3 - 1;
        const int prow = yq + ky * d + 6;
        const int pxb = n + kx * d + 6;
        const int pixb = prow * EX + pxb;
        short8 bf[4];
#pragma unroll
        for (int r = 0; r < 4; ++r)
          bf[r] = *reinterpret_cast<const short8*>(&cb[(pixb + r * EX) * 4]);
        const short8 a8 = __builtin_bit_cast(short8, af[tap]);
#pragma unroll
        for (int r = 0; r < 4; ++r)
          acc[r] =
              __builtin_amdgcn_mfma_f32_32x32x16_bf16(a8, bf[r], acc[r], 0, 0, 0);
      }
    }

    // ---- store slot: D col=lane&31 -> x, row=(reg&3)+8*(reg>>2)+4*h ----
    // row is the compressed item row; mask row<g, oc = perm[start+row].
#pragma unroll
    for (int reg = 0; reg < 16; ++reg) {
      const int row = (reg & 3) + 8 * (reg >> 2) + 4 * h;
      if (row < g) {
        const int oc = desc[start + row];
        float* op =
            &out[((size_t)(b * C_ + oc) * HW_ + (y0 + yq)) * HW_ + x0 + n];
#pragma unroll
        for (int r = 0; r < 4; ++r) op[r * HW_] = acc[r][reg];
      }
    }
  }
}

extern "C" void kernel_launch(void* const* d_in, const int* in_sizes, int n_in,
                              void* d_out, int out_size, void* d_ws,
                              size_t ws_size, hipStream_t stream) {
  const float* x = (const float*)d_in[0];    // [16,64,128,128] fp32
  const float* w = (const float*)d_in[1];    // [64,64,3,3] fp32
  const int* offsets = (const int*)d_in[2];  // [64] int32 in [1,6]
  float* out = (float*)d_out;                // [16,64,128,128] fp32

  int* desc = (int*)d_ws;
  uint4* wpack = (uint4*)((char*)d_ws + WS_WPACK_OFF);  // 442368 B
  unsigned short* xb16 = (unsigned short*)((char*)d_ws + WS_XB16_OFF);

  // Fast path needs 1 MB (desc+wpack) + 40.1 MB (xb16) of workspace.
  const bool pre = ws_size >= (size_t)WS_XB16_OFF + XB16_BYTES;
  const int nrow = pre ? B_ * PADW : 0;

  gsd_prep<<<dim3(nrow + 1 + MAX_ITEMS), 256, 0, stream>>>(
      x, offsets, w, desc, wpack, xb16, nrow);
  if (pre) {
    gsd_conv<true><<<dim3(B_ * 8 * 4), 768, 0, stream>>>(
        x, xb16, desc, wpack, out);
  } else {
    gsd_conv<false><<<dim3(B_ * 8 * 4), 768, 0, stream>>>(
        x, xb16, desc, wpack, out);
  }
}

// Round 9
// 182.623 us; speedup vs baseline: 1.1570x; 1.0975x over previous
//
#include <hip/hip_runtime.h>

// GroupGSDConv round 13: R7 structure + conflict-free h-plane LDS.
// Cross-round record: R7 (2 blocks/CU, 4 waves/SIMD, 2-phase dbuf) = 80us
// with 7.6M conflict cycles; R9-R12 (1 block/CU all-planes variants) =
// 88-100us with 0 conflicts. Combine the winners:
//  - 2-phase double-buffered per-ks staging, 2 x 39936B LDS buffers,
//    (512,4) -> 2 blocks/CU, 16 waves/CU (4/SIMD). One barrier per ks.
//  - Octile shared-accumulator compute (R7): waves (o, rq); items of
//    octile o accumulate into ONE acc[4] (zero-masked A rows make the
//    shared acc safe) -> no VGPR pressure, ks-outer dbuf legal.
//  - h-plane LDS layout (R11, measured 0 conflicts): plane = [h][pix]
//    halves, 16B/pixel records; ds_read_b128 walks pix at 16B stride.
//    Staging source picks ic-half p directly -- NO xor swizzle anywhere.
//  - ks-plane xb16 [B][4][140][140][16ch] (R7, FETCH 21MB), XCD swizzle.
// Fallback (small ws): per-ks in-kernel fp32 staging, single buffer,
// same h-plane addressing.

#define HW_ 128
#define C_ 64
#define B_ 16
#define EX 44
#define EY 28
#define NPIX (EY * EX)              // 1232 staged pixels
#define CHPP (NPIX * 2)             // 2464 16B chunks per plane
#define NSETS 39                    // ceil(2464/64) wave-chunk sets
#define PLANEDW (NSETS * 64 * 4)    // 9984 dwords = 39936 B per buffer
#define HDW (NPIX * 4)              // 4928 dwords per half-plane
#define PADW 140
#define PLANE_STRIDE (PADW * PADW * 16)  // shorts per ks-plane (313600)
#define MAX_ITEMS 12
#define WS_WPACK_OFF 1024
#define WS_XB16_OFF (1 << 20)
#define XB16_BYTES ((size_t)B_ * 4 * PLANE_STRIDE * 2)  // 40,140,800

// desc layout (ints):
//  [0..63]        perm (sorted-by-dilation channel ids)
//  [64+t]         cnt_t   (items in octile t, t<2)
//  [66+t*6+s]     dilation of item (t,s)
//  [78+t*6+s]     wix (wpack index) of item (t,s)
//  [90]           ni_total

typedef __attribute__((ext_vector_type(8))) short short8;
typedef __attribute__((ext_vector_type(16))) float floatx16;

__device__ __forceinline__ unsigned bf16rne(float f) {
  unsigned u = __float_as_uint(f);
  return (u + 0x7FFFu + ((u >> 16) & 1u)) >> 16;  // round-nearest-even
}

#define GLOAD_LDS16(g, l)                                   \
  __builtin_amdgcn_global_load_lds(                         \
      (const __attribute__((address_space(1))) void*)(g),   \
      (__attribute__((address_space(3))) void*)(l), 16, 0, 0)

__global__ __launch_bounds__(256) void gsd_prep(
    const float* __restrict__ x, const int* __restrict__ offsets,
    const float* __restrict__ w, int* __restrict__ desc,
    uint4* __restrict__ wpack, unsigned short* __restrict__ xb16,
    const int nrow) {
  const int bid = blockIdx.x;
  const int tid = threadIdx.x;

  if (bid < nrow) {
    // ---- transpose+convert one padded row into 4 ks-planes ----
    // per plane-row: 140 px * 16 ch * 2B = 4480 B = 280 uint4 (2/px)
    const int b = bid / PADW, py = bid - b * PADW;
    uint4* o4 = (uint4*)xb16;
    const size_t pb0 = ((size_t)b * 4) * 39200 + (size_t)py * 280;
    const uint4 z = make_uint4(0, 0, 0, 0);
    if (py < 6 || py >= PADW - 6) {
      for (int i = tid; i < 1120; i += 256) {
        const int ks = i / 280, r = i - ks * 280;
        o4[pb0 + (size_t)ks * 39200 + r] = z;
      }
      return;
    }
    // x-pads: per plane-row, uint4 0..11 and 268..279
    if (tid < 96) {
      const int ks = tid / 24, rr = tid - ks * 24;
      const int idx = rr < 12 ? rr : 256 + rr;
      o4[pb0 + (size_t)ks * 39200 + idx] = z;
    }
    const int y = py - 6;
    __shared__ unsigned l32[128 * 33];  // [x][c-pair], +1 pad
    const int xx = tid & 127, ph = tid >> 7;
    const float* xp = x + (size_t)b * (C_ * HW_ * HW_) + y * HW_ + xx;
#pragma unroll 4
    for (int p = ph; p < 32; p += 2) {
      const float v0 = xp[(2 * p) * (HW_ * HW_)];
      const float v1 = xp[(2 * p + 1) * (HW_ * HW_)];
      l32[xx * 33 + p] = bf16rne(v0) | (bf16rne(v1) << 16);
    }
    __syncthreads();
#pragma unroll 4
    for (int ch = tid; ch < 1024; ch += 256) {  // 4 planes * 128 px * 2
      const int ks = ch >> 8, r = ch & 255;
      const unsigned* s = &l32[(r >> 1) * 33 + ks * 8 + (r & 1) * 4];
      o4[pb0 + (size_t)ks * 39200 + 12 + r] = make_uint4(s[0], s[1], s[2], s[3]);
    }
    return;
  }

  // ---- setup role (tail blocks; every block recomputes sd) ----
  __shared__ int sd[128];
  __shared__ int soffs[C_];
  if (tid < C_) soffs[tid] = offsets[tid];
  __syncthreads();
  if (tid < C_) {  // parallel stable rank sort by (dilation, channel)
    const int key = soffs[tid];
    int rank = 0;
    for (int c = 0; c < C_; ++c) {
      const int kc = soffs[c];
      rank += (int)((kc < key) | ((kc == key) & (c < tid)));
    }
    sd[rank] = tid;
  }
  __syncthreads();
  if (tid == 0) {
    int ni = 0;
    for (int t = 0; t < 2; ++t) {
      int cnt = 0, prev = -1;
      for (int m = 0; m < 32; ++m) {
        const int dd = soffs[sd[t * 32 + m]];
        if (dd != prev && cnt < 6 && ni < MAX_ITEMS) {
          sd[66 + t * 6 + cnt] = dd;
          sd[78 + t * 6 + cnt] = ni;
          sd[91 + ni * 2] = t;
          sd[92 + ni * 2] = dd;
          ++ni;
          ++cnt;
          prev = dd;
        }
      }
      sd[64 + t] = cnt;
    }
    sd[90] = ni;
  }
  __syncthreads();

  const int sbid = bid - nrow;
  if (sbid == 0) {
    if (tid < 91) desc[tid] = sd[tid];
    return;
  }
  const int wix = sbid - 1;
  if (wix >= sd[90]) return;
  const int o = sd[91 + wix * 2];
  const int dit = sd[92 + wix * 2];

  // Pack A-frags: wpack[wix*2304 + ((ks*9+tap)*64+lane)], element layout
  // m = lane&31 (octile row), k = (lane>>5)*8 + j, ic = ks*16 + k.
  // Rows of other dilations zero-masked -> shared accumulator is safe.
  for (int i = tid; i < 4 * 9 * 64; i += 256) {
    const int ks = i / 576;
    const int r = i % 576;
    const int tap = r >> 6;
    const int lane = r & 63;
    const int m = lane & 31, hh = lane >> 5;
    const int oc = sd[o * 32 + m];
    const bool act = (soffs[oc] == dit);
    unsigned ww[4];
    for (int jj = 0; jj < 4; ++jj) {
      float v0 = 0.f, v1 = 0.f;
      if (act) {
        const int ic0 = ks * 16 + hh * 8 + jj * 2;
        v0 = w[(oc * C_ + ic0) * 9 + tap];
        v1 = w[(oc * C_ + ic0 + 1) * 9 + tap];
      }
      ww[jj] = bf16rne(v0) | (bf16rne(v1) << 16);
    }
    wpack[(size_t)wix * 2304 + i] = make_uint4(ww[0], ww[1], ww[2], ww[3]);
  }
}

template <bool PRE>
__global__ __launch_bounds__(512, 4) void gsd_conv(
    const float* __restrict__ x, const unsigned short* __restrict__ xb16,
    const int* __restrict__ desc, const uint4* __restrict__ wpack,
    float* __restrict__ out) {
  const int tid = threadIdx.x;
  const int bid0 = blockIdx.x;
  const int gxid = (bid0 & 7) * 64 + (bid0 >> 3);  // XCD swizzle (512%8==0)
  const int b = gxid >> 5;
  const int yt = (gxid >> 2) & 7;
  const int xt = gxid & 3;
  const int y0 = yt * 16, x0 = xt * 32;

  const int lane = tid & 63;
  const int n = lane & 31;   // MFMA B col -> output x
  const int h = lane >> 5;   // k-half
  const int wv = tid >> 6;   // 8 waves
  const int o = wv >> 2;     // octile (32 sorted channels)
  const int rq = wv & 3;     // row-quad: y rows rq*4..rq*4+3

  // 2 buffers, each [h][pix] h-plane halves: 79872 B -> 2 blocks/CU
  __shared__ __align__(16) unsigned ldsbuf[2][PLANEDW];

  floatx16 acc[4];
#pragma unroll
  for (int rt = 0; rt < 4; ++rt)
#pragma unroll
    for (int e = 0; e < 16; ++e) acc[rt][e] = 0.f;

  // ---- staging precompute ----
  const unsigned short* xbase;
  int srcoff[5];
  if constexpr (PRE) {
    // Chunk q = (wv + j*8)*64 + lane; LDS dst byte = q*16 (linear).
    // q < NPIX -> half 0 (ic 0..7) of pixel q; else half 1 of q-NPIX.
    // No swizzle: h-plane layout is conflict-free by construction.
    xbase = xb16 + (size_t)b * 4 * PLANE_STRIDE;
#pragma unroll
    for (int j = 0; j < 5; ++j) {
      int q = (wv + j * 8) * 64 + lane;
      if (q > CHPP - 1) q = CHPP - 1;  // set-38 tail -> pad, src clamped
      const int p = q >= NPIX ? 1 : 0;
      const int pix = q - p * NPIX;
      const int yy = pix / EX, xx = pix - yy * EX;
      srcoff[j] = ((y0 + yy) * PADW + (x0 + xx)) * 16 + p * 8;
    }
  }
  int slx, sq, sy2, gxc;
  bool xin;
  const float* xb;
  if constexpr (!PRE) {
    slx = tid & 63;
    sq = (tid >> 6) & 3;  // ic-quad; half p = sq>>1
    sy2 = tid >> 8;
    xb = x + (size_t)b * (C_ * HW_ * HW_);
    const int gx = x0 - 6 + slx;
    gxc = gx < 0 ? 0 : (gx > 127 ? 127 : gx);
    xin = ((unsigned)gx < 128u) & (slx < EX);
  }

  const int cnt = __builtin_amdgcn_readfirstlane(desc[64 + o]);

  // ---- staging: 5 async 16B chunks/wave (wave 7: 4), zero VALU ----
  auto STAGE = [&](int buf, int ks) {
    if constexpr (PRE) {
      const unsigned short* xp = xbase + (size_t)ks * PLANE_STRIDE;
#pragma unroll
      for (int j = 0; j < 5; ++j) {
        if (j < 4 || wv < 7) {  // sets 0..38 only
          GLOAD_LDS16(xp + srcoff[j], &ldsbuf[buf][(wv + j * 8) * 256]);
        }
      }
    }
  };

  // ---- compute: items of this wave's octile, 9 taps x 4 row-tiles ----
  auto COMPUTE = [&](const unsigned* cbuf, int ks) {
    const unsigned* cb = cbuf + h * HDW;  // this lane's ic-half plane
    for (int s = 0; s < cnt; ++s) {
      const int d = __builtin_amdgcn_readfirstlane(desc[66 + o * 6 + s]);
      const int wix = __builtin_amdgcn_readfirstlane(desc[78 + o * 6 + s]);
      const uint4* wp = wpack + ((size_t)wix * 4 + ks) * 576 + lane;
#pragma unroll
      for (int tap = 0; tap < 9; ++tap) {
        const int ky = tap / 3 - 1, kx = tap % 3 - 1;
        const short8 af = __builtin_bit_cast(short8, wp[tap * 64]);
        const int prowb = rq * 4 + ky * d + 6;
        const int pxb = n + kx * d + 6;
#pragma unroll
        for (int rt = 0; rt < 4; ++rt) {
          const int pix = (prowb + rt) * EX + pxb;
          const short8 bf = *reinterpret_cast<const short8*>(&cb[pix * 4]);
          acc[rt] = __builtin_amdgcn_mfma_f32_32x32x16_bf16(af, bf, acc[rt],
                                                            0, 0, 0);
        }
      }
    }
  };

  if constexpr (PRE) {
    // 2-phase pipeline: stage(ks+1) issued before compute(ks); one
    // barrier per ks (drains vmcnt -> staged buffer valid next iter).
    STAGE(0, 0);
    __syncthreads();
#pragma unroll
    for (int ks = 0; ks < 3; ++ks) {
      STAGE((ks + 1) & 1, ks + 1);
      COMPUTE(ldsbuf[ks & 1], ks);
      __syncthreads();
    }
    COMPUTE(ldsbuf[1], 3);
  } else {
    for (int ks = 0; ks < 4; ++ks) {
      if (ks) __syncthreads();
      // fallback: fp32->bf16 in-kernel staging, single buffer, h-plane
      const float* xp = xb + (size_t)(ks * 16 + sq * 4) * (HW_ * HW_);
#pragma unroll 2
      for (int yy = sy2; yy < EY; yy += 2) {
        const int gy = y0 - 6 + yy;
        const int gyc = gy < 0 ? 0 : (gy > 127 ? 127 : gy);
        const bool ok = xin & ((unsigned)gy < 128u);
        const float* p = xp + gyc * HW_ + gxc;
        float v0 = p[0];
        float v1 = p[HW_ * HW_];
        float v2 = p[2 * HW_ * HW_];
        float v3 = p[3 * HW_ * HW_];
        if (!ok) { v0 = v1 = v2 = v3 = 0.f; }
        const unsigned lo = bf16rne(v0) | (bf16rne(v1) << 16);
        const unsigned hi = bf16rne(v2) | (bf16rne(v3) << 16);
        if (slx < EX) {
          const int pix = yy * EX + slx;
          const int dws = (sq >> 1) * HDW + pix * 4 + ((sq & 1) << 1);
          *reinterpret_cast<uint2*>(&ldsbuf[0][dws]) = make_uint2(lo, hi);
        }
      }
      __syncthreads();
      COMPUTE(ldsbuf[0], ks);
    }
  }

  // ---- store: D col=lane&31 -> x, row=(reg&3)+8*(reg>>2)+4*h -> oc ----
  int oc[16];
#pragma unroll
  for (int reg = 0; reg < 16; ++reg) {
    const int row = (reg & 3) + 8 * (reg >> 2) + 4 * h;
    oc[reg] = desc[o * 32 + row];
  }
#pragma unroll
  for (int rt = 0; rt < 4; ++rt) {
    const int y = y0 + rq * 4 + rt;
#pragma unroll
    for (int reg = 0; reg < 16; ++reg) {
      out[((size_t)(b * C_ + oc[reg]) * HW_ + y) * HW_ + x0 + n] =
          acc[rt][reg];
    }
  }
}

extern "C" void kernel_launch(void* const* d_in, const int* in_sizes, int n_in,
                              void* d_out, int out_size, void* d_ws,
                              size_t ws_size, hipStream_t stream) {
  const float* x = (const float*)d_in[0];    // [16,64,128,128] fp32
  const float* w = (const float*)d_in[1];    // [64,64,3,3] fp32
  const int* offsets = (const int*)d_in[2];  // [64] int32 in [1,6]
  float* out = (float*)d_out;                // [16,64,128,128] fp32

  int* desc = (int*)d_ws;
  uint4* wpack = (uint4*)((char*)d_ws + WS_WPACK_OFF);  // 442368 B
  unsigned short* xb16 = (unsigned short*)((char*)d_ws + WS_XB16_OFF);

  // Fast path needs 1 MB (desc+wpack) + 40.1 MB (xb16) of workspace.
  const bool pre = ws_size >= (size_t)WS_XB16_OFF + XB16_BYTES;
  const int nrow = pre ? B_ * PADW : 0;

  gsd_prep<<<dim3(nrow + 1 + MAX_ITEMS), 256, 0, stream>>>(
      x, offsets, w, desc, wpack, xb16, nrow);
  if (pre) {
    gsd_conv<true><<<dim3(B_ * 8 * 4), 512, 0, stream>>>(
        x, xb16, desc, wpack, out);
  } else {
    gsd_conv<false><<<dim3(B_ * 8 * 4), 512, 0, stream>>>(
        x, xb16, desc, wpack, out);
  }
}